// Round 4
// baseline (520.037 us; speedup 1.0000x reference)
//
#include <hip/hip_runtime.h>

#define D_DIM 128
#define HALF_D 64      // float2 per row
#define RPB 64         // rows per bucket
#define RPB_SHIFT 6
#define MAXNB 2048     // LDS histogram bound (NB = 1563 here)
#define CHUNK 2048     // edges staged/sorted per LDS pass

// ---------------- phase 1: coarse bucket histogram ----------------
__global__ void bucket_hist(const int* __restrict__ row, int* __restrict__ counts,
                            int E, int NB) {
    __shared__ int h[MAXNB];
    for (int i = threadIdx.x; i < NB; i += blockDim.x) h[i] = 0;
    __syncthreads();
    int chunk = (E + gridDim.x - 1) / gridDim.x;
    int lo = blockIdx.x * chunk;
    int hi = min(E, lo + chunk);
    for (int e = lo + threadIdx.x; e < hi; e += blockDim.x)
        atomicAdd(&h[row[e] >> RPB_SHIFT], 1);
    __syncthreads();
    for (int i = threadIdx.x; i < NB; i += blockDim.x)
        if (h[i]) atomicAdd(&counts[i], h[i]);
}

// ---------------- phase 2: scan bucket counts (one block) ----------------
__global__ __launch_bounds__(256) void bucket_scan(const int* __restrict__ counts,
                                                   int* __restrict__ off,
                                                   int* __restrict__ cursor, int NB) {
    __shared__ int tot[256];
    int t = threadIdx.x;
    int vals[8];
    int cnts[8];
    int s = 0;
    for (int k = 0; k < 8; ++k) {
        int i = t * 8 + k;
        int c = (i < NB) ? counts[i] : 0;
        cnts[k] = c;
        s += c;
        vals[k] = s;                 // inclusive within thread
    }
    tot[t] = s;
    __syncthreads();
    for (int d = 1; d < 256; d <<= 1) {   // Hillis-Steele inclusive
        int v = (t >= d) ? tot[t - d] : 0;
        __syncthreads();
        tot[t] += v;
        __syncthreads();
    }
    int base = (t > 0) ? tot[t - 1] : 0;
    for (int k = 0; k < 8; ++k) {
        int i = t * 8 + k;
        if (i < NB) {
            int incl = base + vals[k];
            off[i + 1] = incl;
            cursor[i] = incl - cnts[k];   // exclusive prefix = bucket start
        }
    }
    if (t == 0) off[0] = 0;
}

// ---------------- phase 3: bucketed scatter, block-local reservation ----------------
// Each block histograms its ~12.5K-edge chunk in LDS, reserves one contiguous
// run per bucket (single global atomic), then scatters. Runs ~8 edges = 64B
// => cache lines fill before eviction (R2 measured: no write amplification).
__global__ __launch_bounds__(1024) void bucket_scatter(const int* __restrict__ row,
        const int* __restrict__ col, const float* __restrict__ val,
        int* __restrict__ cursor, int2* __restrict__ sorted, int E, int NB) {
    __shared__ int h[MAXNB];
    for (int i = threadIdx.x; i < NB; i += blockDim.x) h[i] = 0;
    __syncthreads();
    int chunk = (E + gridDim.x - 1) / gridDim.x;
    int lo = blockIdx.x * chunk;
    int hi = min(E, lo + chunk);
    for (int e = lo + threadIdx.x; e < hi; e += blockDim.x)
        atomicAdd(&h[row[e] >> RPB_SHIFT], 1);
    __syncthreads();
    for (int i = threadIdx.x; i < NB; i += blockDim.x) {
        int c = h[i];
        h[i] = c ? atomicAdd(&cursor[i], c) : 0;   // h[i] becomes local write cursor
    }
    __syncthreads();
    for (int e = lo + threadIdx.x; e < hi; e += blockDim.x) {
        int r = row[e];
        int b = r >> RPB_SHIFT;
        int p = atomicAdd(&h[b], 1);
        // pack: low 20 bits = col (N < 2^20), bits 20..25 = local row
        sorted[p] = make_int2(col[e] | ((r & (RPB - 1)) << 20), __float_as_int(val[e]));
    }
}

// ---------------- phase 4: fused sort+aggregate, one block per bucket ----------------
// 16 waves/block. Per <=2048-edge chunk: LDS counting-sort by local row (64
// bins), then wave w aggregates rows 4w..4w+3 from its contiguous LDS
// segments with register accumulators (R1-proven inner loop: lane t owns
// float2 cols (2t,2t+1); per edge one coalesced 512B h read; no atomics).
__global__ __launch_bounds__(1024) void aggregate_fused(const int* __restrict__ off,
        const int2* __restrict__ sorted, const float2* __restrict__ h2,
        const float2* __restrict__ h02, float2* __restrict__ out2, int N) {
    __shared__ int2 lds_e[CHUNK];
    __shared__ int cnt[RPB];
    __shared__ int seg[RPB + 1];
    __shared__ int cur[RPB];
    int b = blockIdx.x;
    int tid = threadIdx.x;
    int w = tid >> 6;      // wave 0..15
    int t = tid & 63;      // lane
    int start = off[b], end = off[b + 1];

    float2 acc[4];
    acc[0] = acc[1] = acc[2] = acc[3] = make_float2(0.f, 0.f);

    for (int base = start; base < end; base += CHUNK) {
        int n = min(CHUNK, end - base);
        if (tid < RPB) cnt[tid] = 0;
        __syncthreads();
        // pass 1: histogram local rows
        for (int i = tid; i < n; i += 1024)
            atomicAdd(&cnt[(sorted[base + i].x >> 20) & (RPB - 1)], 1);
        __syncthreads();
        // wave 0: 64-lane inclusive scan of cnt -> seg[1..64]
        if (w == 0) {
            int x = cnt[t];
            int s = x;
            for (int d = 1; d < 64; d <<= 1) {
                int v = __shfl_up(s, d, 64);
                if (t >= d) s += v;
            }
            seg[t + 1] = s;
            cur[t] = s - x;      // exclusive prefix
            if (t == 0) seg[0] = 0;
        }
        __syncthreads();
        // pass 2: scatter into LDS in row-sorted order (re-read: L1/L2-hot)
        for (int i = tid; i < n; i += 1024) {
            int2 e = sorted[base + i];
            int lrow = (e.x >> 20) & (RPB - 1);
            int p = atomicAdd(&cur[lrow], 1);
            lds_e[p] = make_int2(e.x & 0xFFFFF, e.y);
        }
        __syncthreads();
        // aggregate: wave w owns local rows 4w..4w+3
        for (int r = 0; r < 4; ++r) {
            int lr = 4 * w + r;
            int js = seg[lr], je = seg[lr + 1];
            float ax = acc[r].x, ay = acc[r].y;
            for (int j = js; j < je; ++j) {
                int2 e = lds_e[j];               // wave-uniform -> LDS broadcast
                int c = e.x;
                float v = __int_as_float(e.y);
                float2 hc = h2[(size_t)c * HALF_D + t];
                ax = fmaf(v, hc.x, ax);
                ay = fmaf(v, hc.y, ay);
            }
            acc[r].x = ax; acc[r].y = ay;
        }
        __syncthreads();   // protect cnt/seg/cur/lds_e before next chunk
    }
    // epilogue: wave w writes rows 4w..4w+3
    int row0 = b << RPB_SHIFT;
    for (int r = 0; r < 4; ++r) {
        int rr = row0 + 4 * w + r;
        if (rr < N) {
            float2 g = h02[(size_t)rr * HALF_D + t];
            float2 o;
            o.x = fmaf(0.9f, acc[r].x, 0.1f * g.x);
            o.y = fmaf(0.9f, acc[r].y, 0.1f * g.y);
            out2[(size_t)rr * HALF_D + t] = o;
        }
    }
}

// ---------------- fallback: direct atomic scatter ----------------
__global__ void init_out(const float* __restrict__ h0, float* __restrict__ out, int n) {
    int i = blockIdx.x * blockDim.x + threadIdx.x;
    if (i < n) out[i] = 0.1f * h0[i];
}

__global__ void scatter_atomic(const int* __restrict__ row, const int* __restrict__ col,
                               const float* __restrict__ val, const float* __restrict__ h,
                               float* __restrict__ out, int E) {
    long idx = (long)blockIdx.x * blockDim.x + threadIdx.x;
    int e = (int)(idx >> 6);
    if (e >= E) return;
    int t = (int)(idx & 63);
    int r = row[e], c = col[e];
    float v = 0.9f * val[e];
    atomicAdd(&out[(size_t)r * D_DIM + 2 * t],     v * h[(size_t)c * D_DIM + 2 * t]);
    atomicAdd(&out[(size_t)r * D_DIM + 2 * t + 1], v * h[(size_t)c * D_DIM + 2 * t + 1]);
}

extern "C" void kernel_launch(void* const* d_in, const int* in_sizes, int n_in,
                              void* d_out, int out_size, void* d_ws, size_t ws_size,
                              hipStream_t stream) {
    const int*   edge_row = (const int*)d_in[0];
    const int*   edge_col = (const int*)d_in[1];
    const float* edge_val = (const float*)d_in[2];
    const float* h        = (const float*)d_in[3];
    const float* h0       = (const float*)d_in[4];
    float*       out      = (float*)d_out;

    const int E = in_sizes[0];
    const int N = in_sizes[3] / D_DIM;
    const int NB = (N + RPB - 1) / RPB;

    auto align16 = [](size_t x) { return (x + 15) & ~(size_t)15; };
    size_t counts_off = 0;
    size_t off_off    = align16(counts_off + (size_t)NB * 4);
    size_t cursor_off = align16(off_off + (size_t)(NB + 1) * 4);
    size_t sorted_off = align16(cursor_off + (size_t)NB * 4);
    size_t total_ws   = sorted_off + (size_t)E * 8;

    char* ws = (char*)d_ws;
    bool ok = (ws_size >= total_ws) && (NB <= MAXNB) && (N < (1 << 20));
    if (ok) {
        int*  counts = (int*)(ws + counts_off);
        int*  offs   = (int*)(ws + off_off);
        int*  cursor = (int*)(ws + cursor_off);
        int2* sorted = (int2*)(ws + sorted_off);

        hipMemsetAsync(counts, 0, (size_t)NB * 4, stream);
        bucket_hist<<<256, 256, 0, stream>>>(edge_row, counts, E, NB);
        bucket_scan<<<1, 256, 0, stream>>>(counts, offs, cursor, NB);
        bucket_scatter<<<256, 1024, 0, stream>>>(edge_row, edge_col, edge_val,
                                                 cursor, sorted, E, NB);
        aggregate_fused<<<NB, 1024, 0, stream>>>(offs, sorted,
                                                 (const float2*)h, (const float2*)h0,
                                                 (float2*)out, N);
    } else {
        int nd = N * D_DIM;
        init_out<<<(nd + 255) / 256, 256, 0, stream>>>(h0, out, nd);
        long total_threads = (long)E * 64;
        scatter_atomic<<<(int)((total_threads + 255) / 256), 256, 0, stream>>>(
            edge_row, edge_col, edge_val, h, out, E);
    }
}

// Round 5
// 433.747 us; speedup vs baseline: 1.1989x; 1.1989x over previous
//
#include <hip/hip_runtime.h>

#define D_DIM 128
#define HALF_D 64      // float2 / packed-bf16x2 elements per row
#define RPB 64         // rows per bucket
#define RPB_SHIFT 6
#define MAXNB 2048     // LDS histogram bound (NB = 1563 here)

// ---------------- phase 0: h -> packed bf16 (RNE) ----------------
// hb[i] = bf16(h[2i]) in low 16 | bf16(h[2i+1]) in high 16
__global__ void convert_h(const float2* __restrict__ h2, unsigned int* __restrict__ hb, int n) {
    int i = blockIdx.x * blockDim.x + threadIdx.x;
    if (i < n) {
        float2 p = h2[i];
        unsigned bx = __float_as_uint(p.x);
        unsigned by = __float_as_uint(p.y);
        unsigned rx = (bx + 0x7FFFu + ((bx >> 16) & 1u)) >> 16;
        unsigned ry = (by + 0x7FFFu + ((by >> 16) & 1u)) & 0xFFFF0000u;
        hb[i] = rx | ry;
    }
}

// ---------------- phase 1: coarse bucket histogram ----------------
__global__ void bucket_hist(const int* __restrict__ row, int* __restrict__ counts,
                            int E, int NB) {
    __shared__ int h[MAXNB];
    for (int i = threadIdx.x; i < NB; i += blockDim.x) h[i] = 0;
    __syncthreads();
    int chunk = (E + gridDim.x - 1) / gridDim.x;
    int lo = blockIdx.x * chunk;
    int hi = min(E, lo + chunk);
    for (int e = lo + threadIdx.x; e < hi; e += blockDim.x)
        atomicAdd(&h[row[e] >> RPB_SHIFT], 1);
    __syncthreads();
    for (int i = threadIdx.x; i < NB; i += blockDim.x)
        if (h[i]) atomicAdd(&counts[i], h[i]);
}

// ---------------- phase 2: scan bucket counts (one block) ----------------
__global__ __launch_bounds__(256) void bucket_scan(const int* __restrict__ counts,
                                                   int* __restrict__ off,
                                                   int* __restrict__ cursor, int NB) {
    __shared__ int tot[256];
    int t = threadIdx.x;
    int vals[8];
    int cnts[8];
    int s = 0;
    for (int k = 0; k < 8; ++k) {
        int i = t * 8 + k;
        int c = (i < NB) ? counts[i] : 0;
        cnts[k] = c;
        s += c;
        vals[k] = s;                 // inclusive within thread
    }
    tot[t] = s;
    __syncthreads();
    for (int d = 1; d < 256; d <<= 1) {   // Hillis-Steele inclusive
        int v = (t >= d) ? tot[t - d] : 0;
        __syncthreads();
        tot[t] += v;
        __syncthreads();
    }
    int base = (t > 0) ? tot[t - 1] : 0;
    for (int k = 0; k < 8; ++k) {
        int i = t * 8 + k;
        if (i < NB) {
            int incl = base + vals[k];
            off[i + 1] = incl;
            cursor[i] = incl - cnts[k];   // exclusive prefix = bucket start
        }
    }
    if (t == 0) off[0] = 0;
}

// ---------------- phase 3: bucketed scatter, block-local reservation ----------------
__global__ __launch_bounds__(1024) void bucket_scatter(const int* __restrict__ row,
        const int* __restrict__ col, const float* __restrict__ val,
        int* __restrict__ cursor, int2* __restrict__ sorted, int E, int NB) {
    __shared__ int h[MAXNB];
    for (int i = threadIdx.x; i < NB; i += blockDim.x) h[i] = 0;
    __syncthreads();
    int chunk = (E + gridDim.x - 1) / gridDim.x;
    int lo = blockIdx.x * chunk;
    int hi = min(E, lo + chunk);
    for (int e = lo + threadIdx.x; e < hi; e += blockDim.x)
        atomicAdd(&h[row[e] >> RPB_SHIFT], 1);
    __syncthreads();
    for (int i = threadIdx.x; i < NB; i += blockDim.x) {
        int c = h[i];
        h[i] = c ? atomicAdd(&cursor[i], c) : 0;   // h[i] becomes local write cursor
    }
    __syncthreads();
    for (int e = lo + threadIdx.x; e < hi; e += blockDim.x) {
        int r = row[e];
        int b = r >> RPB_SHIFT;
        int p = atomicAdd(&h[b], 1);
        // pack: low 20 bits = col (N < 2^20), bits 20..25 = local row
        sorted[p] = make_int2(col[e] | ((r & (RPB - 1)) << 20), __float_as_int(val[e]));
    }
}

// ---------------- phase 4: per-bucket row sort (separate: measured ~20us) ----------------
__global__ __launch_bounds__(256) void row_sort(const int* __restrict__ off,
        const int2* __restrict__ src, int2* __restrict__ dst,
        int* __restrict__ row_off, int N, int NB, int E) {
    __shared__ int cnt[RPB];
    __shared__ int cur[RPB];
    int b = blockIdx.x;
    int tid = threadIdx.x;
    if (tid < RPB) cnt[tid] = 0;
    __syncthreads();
    int start = off[b], end = off[b + 1];
    for (int i = start + tid; i < end; i += 256)
        atomicAdd(&cnt[(src[i].x >> 20) & (RPB - 1)], 1);
    __syncthreads();
    if (tid == 0) {                       // tiny serial scan: 64 adds
        int s = start;
        for (int i = 0; i < RPB; ++i) { cur[i] = s; s += cnt[i]; }
    }
    __syncthreads();
    int row0 = b << RPB_SHIFT;
    if (tid < RPB && row0 + tid < N) row_off[row0 + tid] = cur[tid];
    if (b == NB - 1 && tid == 0) row_off[N] = E;
    __syncthreads();                      // row_off reads done before cur mutates
    for (int i = start + tid; i < end; i += 256) {
        int2 e = src[i];
        int lrow = (e.x >> 20) & (RPB - 1);
        int p = atomicAdd(&cur[lrow], 1);
        dst[p] = make_int2(e.x & 0xFFFFF, e.y);   // pure col + val
    }
}

// ---------------- phase 5: aggregation, one row per 64-thread wave, bf16 gather ----------------
// lane t loads one packed uint (2 bf16) => 256B coalesced per edge; fp32 accum.
__global__ __launch_bounds__(64) void aggregate_bf16(const int* __restrict__ row_off,
                                                     const int2* __restrict__ ed,
                                                     const unsigned int* __restrict__ hb,
                                                     const float2* __restrict__ h02,
                                                     float2* __restrict__ out2) {
    __shared__ int2 lds[64];
    int r = blockIdx.x;
    int t = threadIdx.x;
    int start = row_off[r];
    int end   = row_off[r + 1];
    float ax = 0.0f, ay = 0.0f;
    for (int base = start; base < end; base += 64) {
        int n = end - base;
        if (n > 64) n = 64;
        if (t < n) lds[t] = ed[base + t];
        __syncthreads();
        for (int j = 0; j < n; ++j) {
            int c = lds[j].x;
            float v = __int_as_float(lds[j].y);
            unsigned u = hb[(size_t)c * HALF_D + t];
            float hx = __uint_as_float(u << 16);
            float hy = __uint_as_float(u & 0xFFFF0000u);
            ax = fmaf(v, hx, ax);
            ay = fmaf(v, hy, ay);
        }
        __syncthreads();
    }
    float2 g = h02[(size_t)r * HALF_D + t];
    float2 o;
    o.x = fmaf(0.9f, ax, 0.1f * g.x);
    o.y = fmaf(0.9f, ay, 0.1f * g.y);
    out2[(size_t)r * HALF_D + t] = o;
}

// fp32 variant (used only if ws can't fit the bf16 copy of h)
__global__ __launch_bounds__(64) void aggregate_f32(const int* __restrict__ row_off,
                                                    const int2* __restrict__ ed,
                                                    const float2* __restrict__ h2,
                                                    const float2* __restrict__ h02,
                                                    float2* __restrict__ out2) {
    __shared__ int2 lds[64];
    int r = blockIdx.x;
    int t = threadIdx.x;
    int start = row_off[r];
    int end   = row_off[r + 1];
    float ax = 0.0f, ay = 0.0f;
    for (int base = start; base < end; base += 64) {
        int n = end - base;
        if (n > 64) n = 64;
        if (t < n) lds[t] = ed[base + t];
        __syncthreads();
        for (int j = 0; j < n; ++j) {
            int c = lds[j].x;
            float v = __int_as_float(lds[j].y);
            float2 hc = h2[(size_t)c * HALF_D + t];
            ax = fmaf(v, hc.x, ax);
            ay = fmaf(v, hc.y, ay);
        }
        __syncthreads();
    }
    float2 g = h02[(size_t)r * HALF_D + t];
    float2 o;
    o.x = fmaf(0.9f, ax, 0.1f * g.x);
    o.y = fmaf(0.9f, ay, 0.1f * g.y);
    out2[(size_t)r * HALF_D + t] = o;
}

// ---------------- fallback: direct atomic scatter ----------------
__global__ void init_out(const float* __restrict__ h0, float* __restrict__ out, int n) {
    int i = blockIdx.x * blockDim.x + threadIdx.x;
    if (i < n) out[i] = 0.1f * h0[i];
}

__global__ void scatter_atomic(const int* __restrict__ row, const int* __restrict__ col,
                               const float* __restrict__ val, const float* __restrict__ h,
                               float* __restrict__ out, int E) {
    long idx = (long)blockIdx.x * blockDim.x + threadIdx.x;
    int e = (int)(idx >> 6);
    if (e >= E) return;
    int t = (int)(idx & 63);
    int r = row[e], c = col[e];
    float v = 0.9f * val[e];
    atomicAdd(&out[(size_t)r * D_DIM + 2 * t],     v * h[(size_t)c * D_DIM + 2 * t]);
    atomicAdd(&out[(size_t)r * D_DIM + 2 * t + 1], v * h[(size_t)c * D_DIM + 2 * t + 1]);
}

extern "C" void kernel_launch(void* const* d_in, const int* in_sizes, int n_in,
                              void* d_out, int out_size, void* d_ws, size_t ws_size,
                              hipStream_t stream) {
    const int*   edge_row = (const int*)d_in[0];
    const int*   edge_col = (const int*)d_in[1];
    const float* edge_val = (const float*)d_in[2];
    const float* h        = (const float*)d_in[3];
    const float* h0       = (const float*)d_in[4];
    float*       out      = (float*)d_out;

    const int E = in_sizes[0];
    const int N = in_sizes[3] / D_DIM;
    const int NB = (N + RPB - 1) / RPB;

    auto align16 = [](size_t x) { return (x + 15) & ~(size_t)15; };
    size_t counts_off  = 0;
    size_t off_off     = align16(counts_off + (size_t)NB * 4);
    size_t cursor_off  = align16(off_off + (size_t)(NB + 1) * 4);
    size_t rowoff_off  = align16(cursor_off + (size_t)NB * 4);
    size_t sorted_off  = align16(rowoff_off + (size_t)(N + 1) * 4);
    size_t sorted2_off = align16(sorted_off + (size_t)E * 8);
    size_t hbf_off     = align16(sorted2_off + (size_t)E * 8);
    size_t ws_f32      = hbf_off;                            // without bf16 h copy
    size_t ws_bf16     = hbf_off + (size_t)N * HALF_D * 4;   // with bf16 h copy

    char* ws = (char*)d_ws;
    bool ok   = (ws_size >= ws_f32) && (NB <= MAXNB) && (N < (1 << 20));
    bool okbf = ok && (ws_size >= ws_bf16);
    if (ok) {
        int*  counts  = (int*)(ws + counts_off);
        int*  offs    = (int*)(ws + off_off);
        int*  cursor  = (int*)(ws + cursor_off);
        int*  row_off = (int*)(ws + rowoff_off);
        int2* sorted  = (int2*)(ws + sorted_off);
        int2* sorted2 = (int2*)(ws + sorted2_off);
        unsigned int* hbf = (unsigned int*)(ws + hbf_off);

        hipMemsetAsync(counts, 0, (size_t)NB * 4, stream);
        if (okbf) {
            int nh = N * HALF_D;
            convert_h<<<(nh + 255) / 256, 256, 0, stream>>>((const float2*)h, hbf, nh);
        }
        bucket_hist<<<256, 256, 0, stream>>>(edge_row, counts, E, NB);
        bucket_scan<<<1, 256, 0, stream>>>(counts, offs, cursor, NB);
        bucket_scatter<<<256, 1024, 0, stream>>>(edge_row, edge_col, edge_val,
                                                 cursor, sorted, E, NB);
        row_sort<<<NB, 256, 0, stream>>>(offs, sorted, sorted2, row_off, N, NB, E);
        if (okbf) {
            aggregate_bf16<<<N, 64, 0, stream>>>(row_off, sorted2, hbf,
                                                 (const float2*)h0, (float2*)out);
        } else {
            aggregate_f32<<<N, 64, 0, stream>>>(row_off, sorted2,
                                                (const float2*)h, (const float2*)h0,
                                                (float2*)out);
        }
    } else {
        int nd = N * D_DIM;
        init_out<<<(nd + 255) / 256, 256, 0, stream>>>(h0, out, nd);
        long total_threads = (long)E * 64;
        scatter_atomic<<<(int)((total_threads + 255) / 256), 256, 0, stream>>>(
            edge_row, edge_col, edge_val, h, out, E);
    }
}